// Round 2
// baseline (6587.077 us; speedup 1.0000x reference)
//
#include <hip/hip_runtime.h>
#include <cstdint>

// VAN checkerboard sampler, LEVEL=0 (odd,odd positions), B=4096, L=16, H=32, K=5.
// One 1024-thread block per batch element; all 64 autoregressive steps in-kernel.
// w2 lives in registers (25 floats per (oc,ic) thread); x / h1-tile / w1 / w3 in LDS.
// Deterministic reductions only (graph replay must revalidate bit-identically).
//
// R2: conv2 inner loop packed into v_pk_fma_f32 (float2 ext-vectors).
//  - gfx950 scalar v_fma_f32 sustains only ~103 TF (m07); the 157.3 TF FP32 peak
//    needs packed FP32. R0/R1 both showed VALUBusy ~85-89% with a 2.2x gap between
//    issued-FMA cycles and VALU-busy cycles, invariant under restructuring =>
//    exec-rate-bound on scalar VOP3 FMA, not spill-junk (VGPR stayed 52 even when
//    offered 128 in R1).
//  - dx-pairs (0,1) and (2,3) share the weight (splat -> op_sel); aligned row pairs
//    P0..P3 come free from the float4 loads, shifted pairs Q0..Q2 built once per tr.
//  - Bit-exact: each acc element's fma chain has identical values in identical
//    (tr asc, kx asc) order; v_pk_fma_f32 = two independent IEEE fp32 FMAs.
//  - Phase 1 reverted to R0's 288-thread version (R1's 864-thread variant added
//    +1.1e8 LDS bank-conflict cycles for no win).

typedef float v2f __attribute__((ext_vector_type(2)));

struct U2 { uint32_t x, y; };

// JAX Threefry-2x32 (20 rounds), matches jax/_src/prng.py
__device__ __forceinline__ U2 tf2x32(uint32_t k0, uint32_t k1, uint32_t x0, uint32_t x1) {
  uint32_t k2 = k0 ^ k1 ^ 0x1BD11BDAu;
#define TFROT(r) { x0 += x1; x1 = (x1 << (r)) | (x1 >> (32 - (r))); x1 ^= x0; }
  x0 += k0; x1 += k1;
  TFROT(13) TFROT(15) TFROT(26) TFROT(6)
  x0 += k1; x1 += k2 + 1u;
  TFROT(17) TFROT(29) TFROT(16) TFROT(24)
  x0 += k2; x1 += k0 + 2u;
  TFROT(13) TFROT(15) TFROT(26) TFROT(6)
  x0 += k0; x1 += k1 + 3u;
  TFROT(17) TFROT(29) TFROT(16) TFROT(24)
  x0 += k1; x1 += k2 + 4u;
  TFROT(13) TFROT(15) TFROT(26) TFROT(6)
  x0 += k2; x1 += k0 + 5u;
#undef TFROT
  return {x0, x1};
}

__device__ __forceinline__ float lrelu(float v) { return fmaxf(v, 0.1f * v); }

__launch_bounds__(1024, 4)
__global__ void van_kernel(const float* __restrict__ gx,
                           const float* __restrict__ gw1, const float* __restrict__ gb1,
                           const float* __restrict__ gw2, const float* __restrict__ gb2,
                           const float* __restrict__ gw3, const float* __restrict__ gb3,
                           float* __restrict__ out, int B) {
  // x field with +/-6 circular halo: array row t <-> field row (t-6)&15
  __shared__ __align__(16) float s_xf[28 * 28];
  __shared__ __align__(16) float s_h1[32][9][12];   // h1 tile, row pitch 12 (16B aligned rows)
  __shared__ __align__(16) float s_w1[800];
  __shared__ __align__(16) float s_w3[800];
  __shared__ __align__(16) float s_buf[8][800];     // reduction tree buffers
  __shared__ float s_b1[32], s_b2[32];
  __shared__ float s_u[64];                          // per-step uniforms for this batch elem
  __shared__ float s_c3[16];                         // per-wave conv3 partials

  const int tid  = threadIdx.x;
  const int bg   = blockIdx.x;
  const int lane = tid & 63;
  const int wv   = tid >> 6;
  const int oc   = tid & 31;   // conv2 out-channel of this thread
  const int ic   = tid >> 5;   // conv2 in-channel of this thread

  // ---------------- init ----------------
  const float b3v = gb3[0];
  float w2r[25];
  {
    const float* p = gw2 + (oc * 32 + ic) * 25;   // w2[oc][ic][ky][kx]
    #pragma unroll
    for (int k = 0; k < 25; ++k) w2r[k] = p[k];
  }
  if (tid < 800) { s_w1[tid] = gw1[tid]; s_w3[tid] = gw3[tid]; }
  if (tid < 32)  { s_b1[tid] = gb1[tid]; s_b2[tid] = gb2[tid]; }
  if (tid < 784) {
    int rr = tid / 28, cc = tid - rr * 28;
    int fy = (rr - 6) & 15, fx = (cc - 6) & 15;
    s_xf[tid] = gx[bg * 256 + fy * 16 + fx];
  }
  if (tid < 64) {
    // jax_threefry_partitionable=True conventions:
    // key_s = threefry(root=(0,42), (0, s)); bits(b) = x^y of threefry(key_s, (0, b))
    U2 key = tf2x32(0u, 42u, 0u, (uint32_t)tid);
    U2 tt  = tf2x32(key.x, key.y, 0u, (uint32_t)bg);
    uint32_t bits = tt.x ^ tt.y;
    s_u[tid] = __uint_as_float(0x3F800000u | (bits >> 9)) - 1.0f;
  }
  float logq = 0.f;   // only thread 0's copy is meaningful
  __syncthreads();

  #pragma unroll 1
  for (int s = 0; s < 64; ++s) {
    const int i = 2 * (s >> 3) + 1;
    const int j = 2 * (s & 7) + 1;

    // ---- phase 1: h1 tile (9x9x32) from x; tile (r,c) <-> field (i-4+r, j-4+c) ----
    if (tid < 288) {
      const int t_ic = tid / 9;
      const int r    = tid - t_ic * 9;
      const float bb = s_b1[t_ic];
      float a[9];
      #pragma unroll
      for (int c = 0; c < 9; ++c) a[c] = bb;
      #pragma unroll
      for (int ky = 0; ky < 5; ++ky) {
        const float* xr = &s_xf[(i + r + ky) * 28 + j];   // field row i-6+r+ky, cols j-6..j+6
        float xv[13];
        #pragma unroll
        for (int m = 0; m < 13; ++m) xv[m] = xr[m];
        #pragma unroll
        for (int kx = 0; kx < 5; ++kx) {
          const float w = s_w1[t_ic * 25 + ky * 5 + kx];
          #pragma unroll
          for (int c = 0; c < 9; ++c) a[c] = fmaf(xv[c + kx], w, a[c]);
        }
      }
      #pragma unroll
      for (int c = 0; c < 9; ++c) s_h1[t_ic][r][c] = lrelu(a[c]);
    }
    __syncthreads();

    // ---- phase 2: conv2 at 25 positions, this thread: (ic, oc) partial ----
    // acc[dy*5+dx]: dx-pairs (0,1) and (2,3) packed as float2 -> v_pk_fma_f32,
    // dx=4 scalar. Per-element fma chain order (tr asc, kx asc) identical to the
    // scalar version => bit-identical results.
    v2f a01[5], a23[5];
    float a4[5];
    #pragma unroll
    for (int dy = 0; dy < 5; ++dy) {
      a01[dy] = (v2f){0.f, 0.f}; a23[dy] = (v2f){0.f, 0.f}; a4[dy] = 0.f;
    }
    #pragma unroll
    for (int tr = 0; tr < 9; ++tr) {
      const float4* rp = (const float4*)(&s_h1[ic][tr][0]);
      const float4 ra = rp[0], rb = rp[1];          // row[0..3], row[4..7]
      const float r8 = s_h1[ic][tr][8];
      // aligned pairs (free from float4) and shifted pairs (built once per tr)
      const v2f P0 = {ra.x, ra.y}, P1 = {ra.z, ra.w}, P2 = {rb.x, rb.y}, P3 = {rb.z, rb.w};
      const v2f Q0 = {ra.y, ra.z}, Q1 = {ra.w, rb.x}, Q2 = {rb.y, rb.z};
      #pragma unroll
      for (int dy = 0; dy < 5; ++dy) {
        const int ky = tr - dy;
        if (ky < 0 || ky > 4) continue;   // folds at compile time (tr,dy unrolled)
#define CONV2_KX(kx, PA, PB, S) \
        { const float w = w2r[ky * 5 + (kx)]; const v2f wv = {w, w}; \
          a01[dy] = __builtin_elementwise_fma(PA, wv, a01[dy]); \
          a23[dy] = __builtin_elementwise_fma(PB, wv, a23[dy]); \
          a4[dy]  = fmaf(S, w, a4[dy]); }
        CONV2_KX(0, P0, P1, rb.x)   // row[kx..], row[kx+2..], row[kx+4]
        CONV2_KX(1, Q0, Q1, rb.y)
        CONV2_KX(2, P1, P2, rb.z)
        CONV2_KX(3, Q1, Q2, rb.w)
        CONV2_KX(4, P2, P3, r8)
#undef CONV2_KX
      }
    }
    // repack to the canonical acc[p] order for the (unchanged) reduction
    float acc[25];
    #pragma unroll
    for (int p = 0; p < 25; ++p) {
      const int dy = p / 5, dx = p % 5;
      acc[p] = (dx < 2) ? a01[dy][dx] : ((dx < 4) ? a23[dy][dx - 2] : a4[dy]);
    }
    // merge ic-pair within wave (lanes l and l^32 share oc)
    #pragma unroll
    for (int p = 0; p < 25; ++p) acc[p] += __shfl_xor(acc[p], 32, 64);
    if (wv >= 8 && lane < 32) {
      #pragma unroll
      for (int p = 0; p < 25; ++p) s_buf[wv - 8][p * 32 + lane] = acc[p];
    }
    __syncthreads();
    if (wv < 8 && lane < 32) {
      #pragma unroll
      for (int p = 0; p < 25; ++p) s_buf[wv][p * 32 + lane] += acc[p];
    }
    __syncthreads();

    // ---- phase 3: final a2 sum (fixed order), lrelu, conv3 partials ----
    float v3 = 0.f;
    if (tid < 800) {
      float t = 0.f;
      #pragma unroll
      for (int v = 0; v < 8; ++v) t += s_buf[v][tid];
      t += s_b2[tid & 31];
      const float h2 = lrelu(t);
      v3 = h2 * s_w3[(tid & 31) * 25 + (tid >> 5)];   // w3[oc][pos]
    }
    #pragma unroll
    for (int m = 32; m >= 1; m >>= 1) v3 += __shfl_xor(v3, m, 64);
    if (lane == 0) s_c3[wv] = v3;
    __syncthreads();

    // ---- phase 4: sample (thread 0), update x field halo copies ----
    if (tid == 0) {
      float logit = b3v;
      #pragma unroll
      for (int v = 0; v < 16; ++v) logit += s_c3[v];
      const float pr   = 1.f / (1.f + expf(-logit));
      const float u    = s_u[s];
      const float samp = (u < pr) ? 1.f : -1.f;
      const int r1 = i + 6, c1 = j + 6;
      const int r2 = (i < 6) ? i + 22 : ((i >= 10) ? i - 10 : r1);
      const int c2 = (j < 6) ? j + 22 : ((j >= 10) ? j - 10 : c1);
      s_xf[r1 * 28 + c1] = samp; s_xf[r1 * 28 + c2] = samp;
      s_xf[r2 * 28 + c1] = samp; s_xf[r2 * 28 + c2] = samp;
      logq += (samp > 0.f) ? logf(pr + 1e-7f) : logf(1.f - pr + 1e-7f);
    }
    __syncthreads();
  }

  // ---------------- output ----------------
  if (tid < 256)
    out[bg * 256 + tid] = s_xf[((tid >> 4) + 6) * 28 + (tid & 15) + 6];
  if (tid == 0)
    out[B * 256 + bg] = logq;
}

extern "C" void kernel_launch(void* const* d_in, const int* in_sizes, int n_in,
                              void* d_out, int out_size, void* d_ws, size_t ws_size,
                              hipStream_t stream) {
  const float* gx  = (const float*)d_in[0];
  const float* gw1 = (const float*)d_in[1];
  const float* gb1 = (const float*)d_in[2];
  const float* gw2 = (const float*)d_in[3];
  const float* gb2 = (const float*)d_in[4];
  const float* gw3 = (const float*)d_in[5];
  const float* gb3 = (const float*)d_in[6];
  float* out = (float*)d_out;
  const int B = in_sizes[0] / 256;

  hipLaunchKernelGGL(van_kernel, dim3(B), dim3(1024), 0, stream,
                     gx, gw1, gb1, gw2, gb2, gw3, gb3, out, B);
}

// Round 3
// 5175.538 us; speedup vs baseline: 1.2727x; 1.2727x over previous
//
#include <hip/hip_runtime.h>
#include <cstdint>

// VAN checkerboard sampler, LEVEL=0 (odd,odd positions), B=4096, L=16, H=32, K=5.
// One 1024-thread block per batch element; all 64 autoregressive steps in-kernel.
// w2 lives in registers (25 floats per (oc,ic) thread); x / h1-tile / w1 / w3 in LDS.
// Deterministic reductions only (graph replay must revalidate bit-identically).
//
// R3: force 2 blocks/CU. R0-R2 all showed OccupancyPercent ~47% = 1 block (16/32
// waves) resident: unified VGPR+AGPR ~116-128/wave blocked the second block, so the
// per-step serial tails (phase1 on 5/16 waves, 2-barrier reduction tree, phase3,
// single-thread sigmoid, 4 barriers) had nothing to overlap with (~5K of the 16K
// cyc/block-step). __launch_bounds__(1024, 8) caps unified regs at 64/wave; the
// phase-2 peak live set is ~63 (acc 25 + w2r 25 + row 9 + addr) so it should fit
// without scratch spill. Everything else is byte-identical to the R0 kernel
// (v_pk_fma_f32 experiment reverted: VOP3P fp32 is half-rate on CDNA4, R2 regressed).

struct U2 { uint32_t x, y; };

// JAX Threefry-2x32 (20 rounds), matches jax/_src/prng.py
__device__ __forceinline__ U2 tf2x32(uint32_t k0, uint32_t k1, uint32_t x0, uint32_t x1) {
  uint32_t k2 = k0 ^ k1 ^ 0x1BD11BDAu;
#define TFROT(r) { x0 += x1; x1 = (x1 << (r)) | (x1 >> (32 - (r))); x1 ^= x0; }
  x0 += k0; x1 += k1;
  TFROT(13) TFROT(15) TFROT(26) TFROT(6)
  x0 += k1; x1 += k2 + 1u;
  TFROT(17) TFROT(29) TFROT(16) TFROT(24)
  x0 += k2; x1 += k0 + 2u;
  TFROT(13) TFROT(15) TFROT(26) TFROT(6)
  x0 += k0; x1 += k1 + 3u;
  TFROT(17) TFROT(29) TFROT(16) TFROT(24)
  x0 += k1; x1 += k2 + 4u;
  TFROT(13) TFROT(15) TFROT(26) TFROT(6)
  x0 += k2; x1 += k0 + 5u;
#undef TFROT
  return {x0, x1};
}

__device__ __forceinline__ float lrelu(float v) { return fmaxf(v, 0.1f * v); }

__launch_bounds__(1024, 8)
__global__ void van_kernel(const float* __restrict__ gx,
                           const float* __restrict__ gw1, const float* __restrict__ gb1,
                           const float* __restrict__ gw2, const float* __restrict__ gb2,
                           const float* __restrict__ gw3, const float* __restrict__ gb3,
                           float* __restrict__ out, int B) {
  // x field with +/-6 circular halo: array row t <-> field row (t-6)&15
  __shared__ __align__(16) float s_xf[28 * 28];
  __shared__ __align__(16) float s_h1[32][9][12];   // h1 tile, row pitch 12 (16B aligned rows)
  __shared__ __align__(16) float s_w1[800];
  __shared__ __align__(16) float s_w3[800];
  __shared__ __align__(16) float s_buf[8][800];     // reduction tree buffers
  __shared__ float s_b1[32], s_b2[32];
  __shared__ float s_u[64];                          // per-step uniforms for this batch elem
  __shared__ float s_c3[16];                         // per-wave conv3 partials

  const int tid  = threadIdx.x;
  const int bg   = blockIdx.x;
  const int lane = tid & 63;
  const int wv   = tid >> 6;
  const int oc   = tid & 31;   // conv2 out-channel of this thread
  const int ic   = tid >> 5;   // conv2 in-channel of this thread

  // ---------------- init ----------------
  const float b3v = gb3[0];
  float w2r[25];
  {
    const float* p = gw2 + (oc * 32 + ic) * 25;   // w2[oc][ic][ky][kx]
    #pragma unroll
    for (int k = 0; k < 25; ++k) w2r[k] = p[k];
  }
  if (tid < 800) { s_w1[tid] = gw1[tid]; s_w3[tid] = gw3[tid]; }
  if (tid < 32)  { s_b1[tid] = gb1[tid]; s_b2[tid] = gb2[tid]; }
  if (tid < 784) {
    int rr = tid / 28, cc = tid - rr * 28;
    int fy = (rr - 6) & 15, fx = (cc - 6) & 15;
    s_xf[tid] = gx[bg * 256 + fy * 16 + fx];
  }
  if (tid < 64) {
    // jax_threefry_partitionable=True conventions:
    // key_s = threefry(root=(0,42), (0, s)); bits(b) = x^y of threefry(key_s, (0, b))
    U2 key = tf2x32(0u, 42u, 0u, (uint32_t)tid);
    U2 tt  = tf2x32(key.x, key.y, 0u, (uint32_t)bg);
    uint32_t bits = tt.x ^ tt.y;
    s_u[tid] = __uint_as_float(0x3F800000u | (bits >> 9)) - 1.0f;
  }
  float logq = 0.f;   // only thread 0's copy is meaningful
  __syncthreads();

  #pragma unroll 1
  for (int s = 0; s < 64; ++s) {
    const int i = 2 * (s >> 3) + 1;
    const int j = 2 * (s & 7) + 1;

    // ---- phase 1: h1 tile (9x9x32) from x; tile (r,c) <-> field (i-4+r, j-4+c) ----
    if (tid < 288) {
      const int t_ic = tid / 9;
      const int r    = tid - t_ic * 9;
      const float bb = s_b1[t_ic];
      float a[9];
      #pragma unroll
      for (int c = 0; c < 9; ++c) a[c] = bb;
      #pragma unroll
      for (int ky = 0; ky < 5; ++ky) {
        const float* xr = &s_xf[(i + r + ky) * 28 + j];   // field row i-6+r+ky, cols j-6..j+6
        float xv[13];
        #pragma unroll
        for (int m = 0; m < 13; ++m) xv[m] = xr[m];
        #pragma unroll
        for (int kx = 0; kx < 5; ++kx) {
          const float w = s_w1[t_ic * 25 + ky * 5 + kx];
          #pragma unroll
          for (int c = 0; c < 9; ++c) a[c] = fmaf(xv[c + kx], w, a[c]);
        }
      }
      #pragma unroll
      for (int c = 0; c < 9; ++c) s_h1[t_ic][r][c] = lrelu(a[c]);
    }
    __syncthreads();

    // ---- phase 2: conv2 at 25 positions, this thread: (ic, oc) partial ----
    float acc[25];
    #pragma unroll
    for (int p = 0; p < 25; ++p) acc[p] = 0.f;
    #pragma unroll
    for (int tr = 0; tr < 9; ++tr) {
      const float4* rp = (const float4*)(&s_h1[ic][tr][0]);
      const float4 ra = rp[0], rb = rp[1];
      const float r8 = s_h1[ic][tr][8];
      const float row[9] = {ra.x, ra.y, ra.z, ra.w, rb.x, rb.y, rb.z, rb.w, r8};
      #pragma unroll
      for (int dy = 0; dy < 5; ++dy) {
        const int ky = tr - dy;
        if (ky < 0 || ky > 4) continue;   // folds at compile time (tr,dy unrolled)
        #pragma unroll
        for (int kx = 0; kx < 5; ++kx) {
          const float w = w2r[ky * 5 + kx];
          #pragma unroll
          for (int dx = 0; dx < 5; ++dx)
            acc[dy * 5 + dx] = fmaf(row[dx + kx], w, acc[dy * 5 + dx]);
        }
      }
    }
    // merge ic-pair within wave (lanes l and l^32 share oc)
    #pragma unroll
    for (int p = 0; p < 25; ++p) acc[p] += __shfl_xor(acc[p], 32, 64);
    if (wv >= 8 && lane < 32) {
      #pragma unroll
      for (int p = 0; p < 25; ++p) s_buf[wv - 8][p * 32 + lane] = acc[p];
    }
    __syncthreads();
    if (wv < 8 && lane < 32) {
      #pragma unroll
      for (int p = 0; p < 25; ++p) s_buf[wv][p * 32 + lane] += acc[p];
    }
    __syncthreads();

    // ---- phase 3: final a2 sum (fixed order), lrelu, conv3 partials ----
    float v3 = 0.f;
    if (tid < 800) {
      float t = 0.f;
      #pragma unroll
      for (int v = 0; v < 8; ++v) t += s_buf[v][tid];
      t += s_b2[tid & 31];
      const float h2 = lrelu(t);
      v3 = h2 * s_w3[(tid & 31) * 25 + (tid >> 5)];   // w3[oc][pos]
    }
    #pragma unroll
    for (int m = 32; m >= 1; m >>= 1) v3 += __shfl_xor(v3, m, 64);
    if (lane == 0) s_c3[wv] = v3;
    __syncthreads();

    // ---- phase 4: sample (thread 0), update x field halo copies ----
    if (tid == 0) {
      float logit = b3v;
      #pragma unroll
      for (int v = 0; v < 16; ++v) logit += s_c3[v];
      const float pr   = 1.f / (1.f + expf(-logit));
      const float u    = s_u[s];
      const float samp = (u < pr) ? 1.f : -1.f;
      const int r1 = i + 6, c1 = j + 6;
      const int r2 = (i < 6) ? i + 22 : ((i >= 10) ? i - 10 : r1);
      const int c2 = (j < 6) ? j + 22 : ((j >= 10) ? j - 10 : c1);
      s_xf[r1 * 28 + c1] = samp; s_xf[r1 * 28 + c2] = samp;
      s_xf[r2 * 28 + c1] = samp; s_xf[r2 * 28 + c2] = samp;
      logq += (samp > 0.f) ? logf(pr + 1e-7f) : logf(1.f - pr + 1e-7f);
    }
    __syncthreads();
  }

  // ---------------- output ----------------
  if (tid < 256)
    out[bg * 256 + tid] = s_xf[((tid >> 4) + 6) * 28 + (tid & 15) + 6];
  if (tid == 0)
    out[B * 256 + bg] = logq;
}

extern "C" void kernel_launch(void* const* d_in, const int* in_sizes, int n_in,
                              void* d_out, int out_size, void* d_ws, size_t ws_size,
                              hipStream_t stream) {
  const float* gx  = (const float*)d_in[0];
  const float* gw1 = (const float*)d_in[1];
  const float* gb1 = (const float*)d_in[2];
  const float* gw2 = (const float*)d_in[3];
  const float* gb2 = (const float*)d_in[4];
  const float* gw3 = (const float*)d_in[5];
  const float* gb3 = (const float*)d_in[6];
  float* out = (float*)d_out;
  const int B = in_sizes[0] / 256;

  hipLaunchKernelGGL(van_kernel, dim3(B), dim3(1024), 0, stream,
                     gx, gw1, gb1, gw2, gb2, gw3, gb3, out, B);
}

// Round 4
// 4996.154 us; speedup vs baseline: 1.3184x; 1.0359x over previous
//
#include <hip/hip_runtime.h>
#include <cstdint>

// VAN checkerboard sampler, LEVEL=0 (odd,odd positions), B=4096, L=16, H=32, K=5.
// One 1024-thread block per batch element; all 64 autoregressive steps in-kernel.
// w2 lives in registers (25 floats per (oc,ic) thread); x / h1-tile / w1 / w3 in LDS.
// Deterministic reductions only (graph replay must revalidate bit-identically).
//
// R4: keep 2 blocks/CU (launch_bounds 1024,8 -- R3: occupancy 47->90%, dur -12%)
// but eliminate the scratch spill R3 introduced (VGPR squeezed to 32, WRITE_SIZE
// 4.2MB -> 299MB). Phase 2 is split into two position passes so the peak live set
// fits the 64-unified-reg budget:
//   pass A: dy in {0,1,2} (15 accs, rows tr 0..6)  -> merge -> s_buf[p<15]
//   pass B: dy in {3,4}   (10 accs, rows tr 3..8)  -> merge -> s_buf[p>=15]
// accA dies before accB is built -> peak live ~50 (w2r 25 + acc 15 + row 9).
// Bit-exact: each acc element's fma chain keeps the identical (tr asc, kx asc)
// order; reduction tree and phase-3 sum orders unchanged.

struct U2 { uint32_t x, y; };

// JAX Threefry-2x32 (20 rounds), matches jax/_src/prng.py
__device__ __forceinline__ U2 tf2x32(uint32_t k0, uint32_t k1, uint32_t x0, uint32_t x1) {
  uint32_t k2 = k0 ^ k1 ^ 0x1BD11BDAu;
#define TFROT(r) { x0 += x1; x1 = (x1 << (r)) | (x1 >> (32 - (r))); x1 ^= x0; }
  x0 += k0; x1 += k1;
  TFROT(13) TFROT(15) TFROT(26) TFROT(6)
  x0 += k1; x1 += k2 + 1u;
  TFROT(17) TFROT(29) TFROT(16) TFROT(24)
  x0 += k2; x1 += k0 + 2u;
  TFROT(13) TFROT(15) TFROT(26) TFROT(6)
  x0 += k0; x1 += k1 + 3u;
  TFROT(17) TFROT(29) TFROT(16) TFROT(24)
  x0 += k1; x1 += k2 + 4u;
  TFROT(13) TFROT(15) TFROT(26) TFROT(6)
  x0 += k2; x1 += k0 + 5u;
#undef TFROT
  return {x0, x1};
}

__device__ __forceinline__ float lrelu(float v) { return fmaxf(v, 0.1f * v); }

__launch_bounds__(1024, 8)
__global__ void van_kernel(const float* __restrict__ gx,
                           const float* __restrict__ gw1, const float* __restrict__ gb1,
                           const float* __restrict__ gw2, const float* __restrict__ gb2,
                           const float* __restrict__ gw3, const float* __restrict__ gb3,
                           float* __restrict__ out, int B) {
  // x field with +/-6 circular halo: array row t <-> field row (t-6)&15
  __shared__ __align__(16) float s_xf[28 * 28];
  __shared__ __align__(16) float s_h1[32][9][12];   // h1 tile, row pitch 12 (16B aligned rows)
  __shared__ __align__(16) float s_w1[800];
  __shared__ __align__(16) float s_w3[800];
  __shared__ __align__(16) float s_buf[8][800];     // reduction tree buffers
  __shared__ float s_b1[32], s_b2[32];
  __shared__ float s_u[64];                          // per-step uniforms for this batch elem
  __shared__ float s_c3[16];                         // per-wave conv3 partials

  const int tid  = threadIdx.x;
  const int bg   = blockIdx.x;
  const int lane = tid & 63;
  const int wv   = tid >> 6;
  const int oc   = tid & 31;   // conv2 out-channel of this thread
  const int ic   = tid >> 5;   // conv2 in-channel of this thread

  // ---------------- init ----------------
  const float b3v = gb3[0];
  float w2r[25];
  {
    const float* p = gw2 + (oc * 32 + ic) * 25;   // w2[oc][ic][ky][kx]
    #pragma unroll
    for (int k = 0; k < 25; ++k) w2r[k] = p[k];
  }
  if (tid < 800) { s_w1[tid] = gw1[tid]; s_w3[tid] = gw3[tid]; }
  if (tid < 32)  { s_b1[tid] = gb1[tid]; s_b2[tid] = gb2[tid]; }
  if (tid < 784) {
    int rr = tid / 28, cc = tid - rr * 28;
    int fy = (rr - 6) & 15, fx = (cc - 6) & 15;
    s_xf[tid] = gx[bg * 256 + fy * 16 + fx];
  }
  if (tid < 64) {
    // jax_threefry_partitionable=True conventions:
    // key_s = threefry(root=(0,42), (0, s)); bits(b) = x^y of threefry(key_s, (0, b))
    U2 key = tf2x32(0u, 42u, 0u, (uint32_t)tid);
    U2 tt  = tf2x32(key.x, key.y, 0u, (uint32_t)bg);
    uint32_t bits = tt.x ^ tt.y;
    s_u[tid] = __uint_as_float(0x3F800000u | (bits >> 9)) - 1.0f;
  }
  float logq = 0.f;   // only thread 0's copy is meaningful
  __syncthreads();

  #pragma unroll 1
  for (int s = 0; s < 64; ++s) {
    const int i = 2 * (s >> 3) + 1;
    const int j = 2 * (s & 7) + 1;

    // ---- phase 1: h1 tile (9x9x32) from x; tile (r,c) <-> field (i-4+r, j-4+c) ----
    if (tid < 288) {
      const int t_ic = tid / 9;
      const int r    = tid - t_ic * 9;
      const float bb = s_b1[t_ic];
      float a[9];
      #pragma unroll
      for (int c = 0; c < 9; ++c) a[c] = bb;
      #pragma unroll
      for (int ky = 0; ky < 5; ++ky) {
        const float* xr = &s_xf[(i + r + ky) * 28 + j];   // field row i-6+r+ky, cols j-6..j+6
        float xv[13];
        #pragma unroll
        for (int m = 0; m < 13; ++m) xv[m] = xr[m];
        #pragma unroll
        for (int kx = 0; kx < 5; ++kx) {
          const float w = s_w1[t_ic * 25 + ky * 5 + kx];
          #pragma unroll
          for (int c = 0; c < 9; ++c) a[c] = fmaf(xv[c + kx], w, a[c]);
        }
      }
      #pragma unroll
      for (int c = 0; c < 9; ++c) s_h1[t_ic][r][c] = lrelu(a[c]);
    }
    __syncthreads();

    // ---- phase 2, pass A: positions dy in {0,1,2} (p = 0..14) ----
    {
      float accA[15];
      #pragma unroll
      for (int p = 0; p < 15; ++p) accA[p] = 0.f;
      #pragma unroll
      for (int tr = 0; tr < 7; ++tr) {
        const float4* rp = (const float4*)(&s_h1[ic][tr][0]);
        const float4 ra = rp[0], rb = rp[1];
        const float r8 = s_h1[ic][tr][8];
        const float row[9] = {ra.x, ra.y, ra.z, ra.w, rb.x, rb.y, rb.z, rb.w, r8};
        #pragma unroll
        for (int dy = 0; dy < 3; ++dy) {
          const int ky = tr - dy;
          if (ky < 0 || ky > 4) continue;   // folds at compile time
          #pragma unroll
          for (int kx = 0; kx < 5; ++kx) {
            const float w = w2r[ky * 5 + kx];
            #pragma unroll
            for (int dx = 0; dx < 5; ++dx)
              accA[dy * 5 + dx] = fmaf(row[dx + kx], w, accA[dy * 5 + dx]);
          }
        }
      }
      // merge ic-pair within wave (lanes l and l^32 share oc)
      #pragma unroll
      for (int p = 0; p < 15; ++p) accA[p] += __shfl_xor(accA[p], 32, 64);
      if (wv >= 8 && lane < 32) {
        #pragma unroll
        for (int p = 0; p < 15; ++p) s_buf[wv - 8][p * 32 + lane] = accA[p];
      }
      __syncthreads();
      if (wv < 8 && lane < 32) {
        #pragma unroll
        for (int p = 0; p < 15; ++p) s_buf[wv][p * 32 + lane] += accA[p];
      }
    }

    // ---- phase 2, pass B: positions dy in {3,4} (p = 15..24) ----
    {
      float accB[10];
      #pragma unroll
      for (int q = 0; q < 10; ++q) accB[q] = 0.f;
      #pragma unroll
      for (int tr = 3; tr < 9; ++tr) {
        const float4* rp = (const float4*)(&s_h1[ic][tr][0]);
        const float4 ra = rp[0], rb = rp[1];
        const float r8 = s_h1[ic][tr][8];
        const float row[9] = {ra.x, ra.y, ra.z, ra.w, rb.x, rb.y, rb.z, rb.w, r8};
        #pragma unroll
        for (int dy = 3; dy < 5; ++dy) {
          const int ky = tr - dy;
          if (ky < 0 || ky > 4) continue;   // folds at compile time
          #pragma unroll
          for (int kx = 0; kx < 5; ++kx) {
            const float w = w2r[ky * 5 + kx];
            #pragma unroll
            for (int dx = 0; dx < 5; ++dx)
              accB[(dy - 3) * 5 + dx] = fmaf(row[dx + kx], w, accB[(dy - 3) * 5 + dx]);
          }
        }
      }
      #pragma unroll
      for (int q = 0; q < 10; ++q) accB[q] += __shfl_xor(accB[q], 32, 64);
      if (wv >= 8 && lane < 32) {
        #pragma unroll
        for (int q = 0; q < 10; ++q) s_buf[wv - 8][(q + 15) * 32 + lane] = accB[q];
      }
      __syncthreads();
      if (wv < 8 && lane < 32) {
        #pragma unroll
        for (int q = 0; q < 10; ++q) s_buf[wv][(q + 15) * 32 + lane] += accB[q];
      }
      __syncthreads();
    }

    // ---- phase 3: final a2 sum (fixed order), lrelu, conv3 partials ----
    float v3 = 0.f;
    if (tid < 800) {
      float t = 0.f;
      #pragma unroll
      for (int v = 0; v < 8; ++v) t += s_buf[v][tid];
      t += s_b2[tid & 31];
      const float h2 = lrelu(t);
      v3 = h2 * s_w3[(tid & 31) * 25 + (tid >> 5)];   // w3[oc][pos]
    }
    #pragma unroll
    for (int m = 32; m >= 1; m >>= 1) v3 += __shfl_xor(v3, m, 64);
    if (lane == 0) s_c3[wv] = v3;
    __syncthreads();

    // ---- phase 4: sample (thread 0), update x field halo copies ----
    if (tid == 0) {
      float logit = b3v;
      #pragma unroll
      for (int v = 0; v < 16; ++v) logit += s_c3[v];
      const float pr   = 1.f / (1.f + expf(-logit));
      const float u    = s_u[s];
      const float samp = (u < pr) ? 1.f : -1.f;
      const int r1 = i + 6, c1 = j + 6;
      const int r2 = (i < 6) ? i + 22 : ((i >= 10) ? i - 10 : r1);
      const int c2 = (j < 6) ? j + 22 : ((j >= 10) ? j - 10 : c1);
      s_xf[r1 * 28 + c1] = samp; s_xf[r1 * 28 + c2] = samp;
      s_xf[r2 * 28 + c1] = samp; s_xf[r2 * 28 + c2] = samp;
      logq += (samp > 0.f) ? logf(pr + 1e-7f) : logf(1.f - pr + 1e-7f);
    }
    __syncthreads();
  }

  // ---------------- output ----------------
  if (tid < 256)
    out[bg * 256 + tid] = s_xf[((tid >> 4) + 6) * 28 + (tid & 15) + 6];
  if (tid == 0)
    out[B * 256 + bg] = logq;
}

extern "C" void kernel_launch(void* const* d_in, const int* in_sizes, int n_in,
                              void* d_out, int out_size, void* d_ws, size_t ws_size,
                              hipStream_t stream) {
  const float* gx  = (const float*)d_in[0];
  const float* gw1 = (const float*)d_in[1];
  const float* gb1 = (const float*)d_in[2];
  const float* gw2 = (const float*)d_in[3];
  const float* gb2 = (const float*)d_in[4];
  const float* gw3 = (const float*)d_in[5];
  const float* gb3 = (const float*)d_in[6];
  float* out = (float*)d_out;
  const int B = in_sizes[0] / 256;

  hipLaunchKernelGGL(van_kernel, dim3(B), dim3(1024), 0, stream,
                     gx, gw1, gb1, gw2, gb2, gw3, gb3, out, B);
}